// Round 11
// baseline (177.100 us; speedup 1.0000x reference)
//
#include <hip/hip_runtime.h>
#include <hip/hip_bf16.h>

typedef __bf16 bf16;
typedef __bf16 bf16x4 __attribute__((ext_vector_type(4)));
typedef __bf16 bf16x8 __attribute__((ext_vector_type(8)));
typedef float  f32x4  __attribute__((ext_vector_type(4)));

// Problem constants: B=16, T=1024, C=512, H=8, Dh=64
#define BB 16
#define TT 1024
#define CC 512
#define HH 8
#define DH 64

// 0.125 (1/sqrt(Dh)) * log2(e): folded into Q so softmax uses exp2 directly.
#define QSCALE 0.18033688011112042f
#define RESCALE_THR 10.0f

__device__ __forceinline__ void gload16(const void* gsrc, void* ldst) {
    __builtin_amdgcn_global_load_lds(
        (const __attribute__((address_space(1))) void*)gsrc,
        (__attribute__((address_space(3))) void*)ldst, 16, 0, 0);
}

__device__ __forceinline__ f32x4 mfma16(bf16x8 a, bf16x8 b, f32x4 c) {
    return __builtin_amdgcn_mfma_f32_16x16x32_bf16(a, b, c, 0, 0, 0);
}

// ---------------- conversion kernels ----------------
__global__ void k_cvt(const float* __restrict__ src, bf16* __restrict__ dst, int n) {
    int i = (blockIdx.x * blockDim.x + threadIdx.x) * 4;
    if (i < n) {
        float4 v = *(const float4*)(src + i);
        bf16x4 o = { (bf16)v.x, (bf16)v.y, (bf16)v.z, (bf16)v.w };
        *(bf16x4*)(dst + i) = o;
    }
}

__global__ void k_cvt_t(const float* __restrict__ src, bf16* __restrict__ dst, int K, int N) {
    int idx = blockIdx.x * blockDim.x + threadIdx.x;
    if (idx < K * N) {
        int k = idx / N, n = idx - k * N;
        dst[(size_t)n * K + k] = (bf16)src[idx];
    }
}

// ---------------- GEMM: C[M,N] = A[M,K] * Bt[N,K]^T ----------------
// BK=64, LDS tile [kk][128][32]. 16 x 1KB linear global_load_lds chunks.
// XCD-aware swizzle. MODE 0: fp32 out. MODE 1: QKV scatter (V^T).
template<int MODE>
__global__ __launch_bounds__(256)
void k_gemm_bt(const bf16* __restrict__ A, const bf16* __restrict__ Bt,
               int M, int N, int K,
               float* __restrict__ outF,
               bf16* __restrict__ qb, bf16* __restrict__ kb, bf16* __restrict__ vtb)
{
    __shared__ bf16 sA[2 * 128 * 32];   // [kk][row][32]
    __shared__ bf16 sB[2 * 128 * 32];
    const int tid  = threadIdx.x;
    const int wid  = tid >> 6;
    const int lane = tid & 63;
    const int l15  = lane & 15, l4 = lane >> 4;

    // XCD swizzle: contiguous grid chunk per XCD -> A-panel L2 reuse
    const int cpx = gridDim.x >> 3;
    const int bid = (blockIdx.x & 7) * cpx + (blockIdx.x >> 3);

    const int nNt = N >> 7;
    const int mt  = bid / nNt;
    const int nt  = bid - mt * nNt;
    const int m0  = mt << 7, n0 = nt << 7;
    const int wr  = (wid >> 1) * 64, wc = (wid & 1) * 64;

    f32x4 zero = {0.f, 0.f, 0.f, 0.f};
    f32x4 acc[4][4];
#pragma unroll
    for (int i = 0; i < 4; ++i)
#pragma unroll
        for (int j = 0; j < 4; ++j) acc[i][j] = zero;

    // staging geometry (per wave: 4 chunks of 512 elements)
    int srow[4], scol[4], soff[4];
#pragma unroll
    for (int c = 0; c < 4; ++c) {
        const int cc = wid * 4 + c;                  // 0..15
        srow[c] = (cc & 7) * 16 + (lane >> 2);       // tile row 0..127
        scol[c] = (cc >> 3) * 32 + (lane & 3) * 8;   // k offset within 64
        soff[c] = cc * 512;                          // LDS elem base (wave-uniform)
    }

    for (int k0 = 0; k0 < K; k0 += 64) {
#pragma unroll
        for (int c = 0; c < 4; ++c)
            gload16(A  + (size_t)(m0 + srow[c]) * K + k0 + scol[c], sA + soff[c]);
#pragma unroll
        for (int c = 0; c < 4; ++c)
            gload16(Bt + (size_t)(n0 + srow[c]) * K + k0 + scol[c], sB + soff[c]);
        __syncthreads();
        bf16x8 af[4][2], bfr[4][2];
#pragma unroll
        for (int kk = 0; kk < 2; ++kk) {
#pragma unroll
            for (int i = 0; i < 4; ++i)
                af[i][kk] = *(const bf16x8*)(sA + kk * 4096 + (wr + i * 16 + l15) * 32 + l4 * 8);
#pragma unroll
            for (int j = 0; j < 4; ++j)
                bfr[j][kk] = *(const bf16x8*)(sB + kk * 4096 + (wc + j * 16 + l15) * 32 + l4 * 8);
        }
#pragma unroll
        for (int kk = 0; kk < 2; ++kk)
#pragma unroll
            for (int i = 0; i < 4; ++i)
#pragma unroll
                for (int j = 0; j < 4; ++j)
                    acc[i][j] = mfma16(af[i][kk], bfr[j][kk], acc[i][j]);
        __syncthreads();
    }

#pragma unroll
    for (int i = 0; i < 4; ++i) {
#pragma unroll
        for (int j = 0; j < 4; ++j) {
#pragma unroll
            for (int rg = 0; rg < 4; ++rg) {
                int rm = m0 + wr + i * 16 + l4 * 4 + rg;
                int cn = n0 + wc + j * 16 + l15;
                float v = acc[i][j][rg];
                if (MODE == 0) {
                    outF[(size_t)rm * N + cn] = v;
                } else {
                    int b = rm >> 10, t = rm & 1023;
                    int s = cn >> 9, h = (cn >> 6) & 7, d = cn & 63;
                    size_t bh = (size_t)(b * HH + h);
                    if (s == 0)      qb [(bh * TT + t) * DH + d] = (bf16)(v * QSCALE);
                    else if (s == 1) kb [(bh * TT + t) * DH + d] = (bf16)v;
                    else             vtb[(bh * DH + d) * TT + t] = (bf16)v;   // V^T scatter
                }
            }
        }
    }
}

// ---------------- flash attention v7: one q-block per block, heavy-first ----------------
// 1024 blocks x 256 thr (4 waves) = 4 blocks/CU. Block owns ONE 128-row q-block
// of one bh; qblk descending within each XCD group so heavy blocks dispatch
// first. Per KV-tile: K (4KB) + V^T (4KB) reg-staged into padded LDS, shared
// by 4 waves. Same per-row arithmetic as v6 (bit-identical output).
__global__ __launch_bounds__(256)
void k_attn(const bf16* __restrict__ qg, const bf16* __restrict__ kg,
            const bf16* __restrict__ vtg, bf16* __restrict__ yb)
{
    __shared__ __align__(16) bf16 sK[2][32 * 72];   // [k-row][dh], row stride 72
    __shared__ __align__(16) bf16 sV[2][64 * 40];   // [d][k],     row stride 40
    __shared__ __align__(16) bf16 sP[4][32 * 40];   // per-wave P tile
    const int tid = threadIdx.x, w = tid >> 6, lane = tid & 63;
    const int l15 = lane & 15, l4 = lane >> 4;

    const int bid = blockIdx.x;              // 0..1023
    const int xcd = bid & 7;
    const int idx = bid >> 3;                // 0..127
    const int bh  = xcd * 16 + (idx >> 3);   // 0..127
    const int qblk = 7 - (idx & 7);          // heavy (qblk=7) first

    const bf16* Q  = qg  + (size_t)bh * TT * DH;
    const bf16* Kp = kg  + (size_t)bh * TT * DH;
    const bf16* Vt = vtg + (size_t)bh * DH * TT;
    const int b = bh >> 3, h = bh & 7;

    const int ks_row = tid >> 3;                  // 0..31
    const int ks_col = (tid & 7) * 8;             // 0..56
    const int vs_row = tid >> 2;                  // 0..63 (d)
    const int vs_col = (tid & 3) * 8;             // 0..24

    bf16* myP = &sP[w][0];
    const f32x4 zero = {0.f, 0.f, 0.f, 0.f};

    const int qbw = qblk * 128 + w * 32;   // this wave's 32 q-rows
    const int nt  = (qblk + 1) * 4;        // causal KV tiles of 32

    bf16x8 qf[2][2];
#pragma unroll
    for (int mi = 0; mi < 2; ++mi)
#pragma unroll
        for (int kk = 0; kk < 2; ++kk)
            qf[mi][kk] = *(const bf16x8*)(Q + (size_t)(qbw + mi * 16 + l15) * DH + kk * 32 + l4 * 8);

    f32x4 y[2][4];
    float m_[2], lp_[2];
#pragma unroll
    for (int mi = 0; mi < 2; ++mi) {
        m_[mi] = -1e30f; lp_[mi] = 0.f;
#pragma unroll
        for (int dj = 0; dj < 4; ++dj) y[mi][dj] = zero;
    }

    {
        uint4 k0 = *(const uint4*)(Kp + (size_t)ks_row * DH + ks_col);
        uint4 v0 = *(const uint4*)(Vt + (size_t)vs_row * TT + vs_col);
        *(uint4*)(&sK[0][ks_row * 72 + ks_col]) = k0;
        *(uint4*)(&sV[0][vs_row * 40 + vs_col]) = v0;
    }
    __syncthreads();

    for (int t = 0; t < nt; ++t) {
        const int t0 = t * 32;
        const int cur = t & 1, nxt = cur ^ 1;
        const bool more = (t + 1 < nt);
        uint4 kreg, vreg;
        if (more) {   // T14: issue next tile's global loads early
            kreg = *(const uint4*)(Kp + (size_t)(t0 + 32 + ks_row) * DH + ks_col);
            vreg = *(const uint4*)(Vt + (size_t)vs_row * TT + t0 + 32 + vs_col);
        }

        if (t0 <= qbw) {   // wave-uniform causal skip
            bf16x8 kf[2][2];
#pragma unroll
            for (int nj = 0; nj < 2; ++nj) {
                const int row = nj * 16 + l15;
#pragma unroll
                for (int kk = 0; kk < 2; ++kk)
                    kf[nj][kk] = *(const bf16x8*)(&sK[cur][row * 72 + ((kk << 2) | l4) * 8]);
            }
            f32x4 s[2][2];
#pragma unroll
            for (int mi = 0; mi < 2; ++mi)
#pragma unroll
                for (int nj = 0; nj < 2; ++nj) {
                    f32x4 a = mfma16(kf[nj][0], qf[mi][0], zero);
                    s[mi][nj] = mfma16(kf[nj][1], qf[mi][1], a);
                }
            if (t0 == qbw) {   // diagonal tile mask
#pragma unroll
                for (int mi = 0; mi < 2; ++mi)
#pragma unroll
                    for (int nj = 0; nj < 2; ++nj)
#pragma unroll
                        for (int rg = 0; rg < 4; ++rg)
                            if (nj * 16 + l4 * 4 + rg > mi * 16 + l15)
                                s[mi][nj][rg] = -1e30f;
            }
#pragma unroll
            for (int mi = 0; mi < 2; ++mi) {
                float mx = fmaxf(fmaxf(fmaxf(s[mi][0][0], s[mi][0][1]), fmaxf(s[mi][0][2], s[mi][0][3])),
                                 fmaxf(fmaxf(s[mi][1][0], s[mi][1][1]), fmaxf(s[mi][1][2], s[mi][1][3])));
                mx = fmaxf(mx, __shfl_xor(mx, 16));
                mx = fmaxf(mx, __shfl_xor(mx, 32));
                if (__any(mx > m_[mi] + RESCALE_THR)) {   // T13 defer-rescale
                    float mnew = fmaxf(m_[mi], mx);
                    float corr = exp2f(m_[mi] - mnew);
                    lp_[mi] *= corr;
                    float cr[4];
#pragma unroll
                    for (int rg = 0; rg < 4; ++rg)
                        cr[rg] = __shfl(corr, ((lane >> 4) << 2) | rg);
#pragma unroll
                    for (int dj = 0; dj < 4; ++dj)
#pragma unroll
                        for (int rg = 0; rg < 4; ++rg) y[mi][dj][rg] *= cr[rg];
                    m_[mi] = mnew;
                }
                bf16x4 pk0, pk1;
#pragma unroll
                for (int rg = 0; rg < 4; ++rg) {
                    float p0 = exp2f(s[mi][0][rg] - m_[mi]);
                    float p1 = exp2f(s[mi][1][rg] - m_[mi]);
                    lp_[mi] += p0 + p1;
                    pk0[rg] = (bf16)p0;
                    pk1[rg] = (bf16)p1;
                }
                *(bf16x4*)(myP + (mi * 16 + l15) * 40 + l4 * 4)      = pk0;
                *(bf16x4*)(myP + (mi * 16 + l15) * 40 + 16 + l4 * 4) = pk1;
            }
            bf16x8 pa[2], vf[4];
#pragma unroll
            for (int mi = 0; mi < 2; ++mi)
                pa[mi] = *(const bf16x8*)(myP + (mi * 16 + l15) * 40 + l4 * 8);
#pragma unroll
            for (int dj = 0; dj < 4; ++dj)
                vf[dj] = *(const bf16x8*)(&sV[cur][(dj * 16 + l15) * 40 + l4 * 8]);
#pragma unroll
            for (int mi = 0; mi < 2; ++mi)
#pragma unroll
                for (int dj = 0; dj < 4; ++dj)
                    y[mi][dj] = mfma16(pa[mi], vf[dj], y[mi][dj]);
        }

        if (more) {   // T14: write-late into the other buffer
            *(uint4*)(&sK[nxt][ks_row * 72 + ks_col]) = kreg;
            *(uint4*)(&sV[nxt][vs_row * 40 + vs_col]) = vreg;
        }
        __syncthreads();
    }

    // epilogue: row denominators, normalize, store
#pragma unroll
    for (int mi = 0; mi < 2; ++mi) {
        float lp = lp_[mi];
        lp += __shfl_xor(lp, 16);
        lp += __shfl_xor(lp, 32);
#pragma unroll
        for (int rg = 0; rg < 4; ++rg) {
            float inv = 1.0f / __shfl(lp, ((lane >> 4) << 2) | rg);
            int rr = qbw + mi * 16 + l4 * 4 + rg;
#pragma unroll
            for (int dj = 0; dj < 4; ++dj) {
                int cc = h * DH + dj * 16 + l15;
                yb[((size_t)b * TT + rr) * CC + cc] = (bf16)(y[mi][dj][rg] * inv);
            }
        }
    }
}

// ---------------- launch ----------------
extern "C" void kernel_launch(void* const* d_in, const int* in_sizes, int n_in,
                              void* d_out, int out_size, void* d_ws, size_t ws_size,
                              hipStream_t stream)
{
    const float* x    = (const float*)d_in[0];   // [16,1024,512]
    const float* wqkv = (const float*)d_in[1];   // [512,1536]
    const float* wout = (const float*)d_in[2];   // [512,512]
    float* out = (float*)d_out;                  // [16,1024,512] fp32

    const size_t NX = (size_t)BB * TT * CC;
    bf16* p   = (bf16*)d_ws;
    bf16* Xb  = p;  p += NX;
    bf16* Wqt = p;  p += (size_t)(3 * CC) * CC;
    bf16* Wot = p;  p += (size_t)CC * CC;
    bf16* Qb  = p;  p += NX;
    bf16* Kb  = p;  p += NX;
    bf16* Vtb = p;  p += NX;
    bf16* Yb  = Xb;                              // alias: Xb dead after GEMM1

    k_cvt  <<<(int)(NX / 4 / 256), 256, 0, stream>>>(x, Xb, (int)NX);
    k_cvt_t<<<(3 * CC * CC + 255) / 256, 256, 0, stream>>>(wqkv, Wqt, CC, 3 * CC);
    k_cvt_t<<<(CC * CC + 255) / 256, 256, 0, stream>>>(wout, Wot, CC, CC);

    // QKV projection with V^T scatter
    k_gemm_bt<1><<<(BB * TT / 128) * (3 * CC / 128), 256, 0, stream>>>(
        Xb, Wqt, BB * TT, 3 * CC, CC, nullptr, Qb, Kb, Vtb);

    // causal flash attention -> Yb (1024 single-q-block blocks)
    k_attn<<<BB * HH * 8, 256, 0, stream>>>(Qb, Kb, Vtb, Yb);

    // output projection -> fp32 out
    k_gemm_bt<0><<<(BB * TT / 128) * (CC / 128), 256, 0, stream>>>(
        Yb, Wot, BB * TT, CC, CC, out, nullptr, nullptr, nullptr);
}

// Round 14
// 156.349 us; speedup vs baseline: 1.1327x; 1.1327x over previous
//
#include <hip/hip_runtime.h>
#include <hip/hip_bf16.h>

typedef __bf16 bf16;
typedef __bf16 bf16x4 __attribute__((ext_vector_type(4)));
typedef __bf16 bf16x8 __attribute__((ext_vector_type(8)));
typedef float  f32x4  __attribute__((ext_vector_type(4)));

// Problem constants: B=16, T=1024, C=512, H=8, Dh=64
#define BB 16
#define TT 1024
#define CC 512
#define HH 8
#define DH 64

// 0.125 (1/sqrt(Dh)) * log2(e): folded into Q so softmax uses exp2 directly.
#define QSCALE 0.18033688011112042f
#define RESCALE_THR 10.0f

__device__ __forceinline__ void gload16(const void* gsrc, void* ldst) {
    __builtin_amdgcn_global_load_lds(
        (const __attribute__((address_space(1))) void*)gsrc,
        (__attribute__((address_space(3))) void*)ldst, 16, 0, 0);
}

__device__ __forceinline__ f32x4 mfma16(bf16x8 a, bf16x8 b, f32x4 c) {
    return __builtin_amdgcn_mfma_f32_16x16x32_bf16(a, b, c, 0, 0, 0);
}

// ---------------- conversion kernels ----------------
__global__ void k_cvt(const float* __restrict__ src, bf16* __restrict__ dst, int n) {
    int i = (blockIdx.x * blockDim.x + threadIdx.x) * 4;
    if (i < n) {
        float4 v = *(const float4*)(src + i);
        bf16x4 o = { (bf16)v.x, (bf16)v.y, (bf16)v.z, (bf16)v.w };
        *(bf16x4*)(dst + i) = o;
    }
}

__global__ void k_cvt_t(const float* __restrict__ src, bf16* __restrict__ dst, int K, int N) {
    int idx = blockIdx.x * blockDim.x + threadIdx.x;
    if (idx < K * N) {
        int k = idx / N, n = idx - k * N;
        dst[(size_t)n * K + k] = (bf16)src[idx];
    }
}

// ---------------- GEMM: C[M,N] = A[M,K] * Bt[N,K]^T ----------------
// BK=64, LDS tile [kk][128][32]. Staging: 16 chunks of 1024 BYTES (=512 bf16)
// via linear global_load_lds. chunk cc covers elements [cc*512, cc*512+512):
// kk=cc>>3, row=(cc&7)*16+(lane>>2), kcol=(lane&3)*8, LDS base=cc*512.
// XCD-aware swizzle. MODE 0: fp32 out. MODE 1: QKV scatter (V^T).
template<int MODE>
__global__ __launch_bounds__(256)
void k_gemm_bt(const bf16* __restrict__ A, const bf16* __restrict__ Bt,
               int M, int N, int K,
               float* __restrict__ outF,
               bf16* __restrict__ qb, bf16* __restrict__ kb, bf16* __restrict__ vtb)
{
    __shared__ bf16 sA[2 * 128 * 32];   // [kk][row][32]
    __shared__ bf16 sB[2 * 128 * 32];
    const int tid  = threadIdx.x;
    const int wid  = tid >> 6;
    const int lane = tid & 63;
    const int l15  = lane & 15, l4 = lane >> 4;

    // XCD swizzle: contiguous grid chunk per XCD -> A-panel L2 reuse
    const int cpx = gridDim.x >> 3;
    const int bid = (blockIdx.x & 7) * cpx + (blockIdx.x >> 3);

    const int nNt = N >> 7;
    const int mt  = bid / nNt;
    const int nt  = bid - mt * nNt;
    const int m0  = mt << 7, n0 = nt << 7;
    const int wr  = (wid >> 1) * 64, wc = (wid & 1) * 64;

    f32x4 zero = {0.f, 0.f, 0.f, 0.f};
    f32x4 acc[4][4];
#pragma unroll
    for (int i = 0; i < 4; ++i)
#pragma unroll
        for (int j = 0; j < 4; ++j) acc[i][j] = zero;

    // staging geometry (per wave: 4 chunks of 512 elements)
    int srow[4], scol[4], soff[4];
#pragma unroll
    for (int c = 0; c < 4; ++c) {
        const int cc = wid * 4 + c;                  // 0..15
        srow[c] = (cc & 7) * 16 + (lane >> 2);       // tile row 0..127
        scol[c] = (cc >> 3) * 32 + (lane & 3) * 8;   // k offset within 64
        soff[c] = cc * 512;                          // LDS elem base (wave-uniform)
    }

    for (int k0 = 0; k0 < K; k0 += 64) {
#pragma unroll
        for (int c = 0; c < 4; ++c)
            gload16(A  + (size_t)(m0 + srow[c]) * K + k0 + scol[c], sA + soff[c]);
#pragma unroll
        for (int c = 0; c < 4; ++c)
            gload16(Bt + (size_t)(n0 + srow[c]) * K + k0 + scol[c], sB + soff[c]);
        __syncthreads();
        bf16x8 af[4][2], bfr[4][2];
#pragma unroll
        for (int kk = 0; kk < 2; ++kk) {
#pragma unroll
            for (int i = 0; i < 4; ++i)
                af[i][kk] = *(const bf16x8*)(sA + kk * 4096 + (wr + i * 16 + l15) * 32 + l4 * 8);
#pragma unroll
            for (int j = 0; j < 4; ++j)
                bfr[j][kk] = *(const bf16x8*)(sB + kk * 4096 + (wc + j * 16 + l15) * 32 + l4 * 8);
        }
#pragma unroll
        for (int kk = 0; kk < 2; ++kk)
#pragma unroll
            for (int i = 0; i < 4; ++i)
#pragma unroll
                for (int j = 0; j < 4; ++j)
                    acc[i][j] = mfma16(af[i][kk], bfr[j][kk], acc[i][j]);
        __syncthreads();
    }

#pragma unroll
    for (int i = 0; i < 4; ++i) {
#pragma unroll
        for (int j = 0; j < 4; ++j) {
#pragma unroll
            for (int rg = 0; rg < 4; ++rg) {
                int rm = m0 + wr + i * 16 + l4 * 4 + rg;
                int cn = n0 + wc + j * 16 + l15;
                float v = acc[i][j][rg];
                if (MODE == 0) {
                    outF[(size_t)rm * N + cn] = v;
                } else {
                    int b = rm >> 10, t = rm & 1023;
                    int s = cn >> 9, h = (cn >> 6) & 7, d = cn & 63;
                    size_t bh = (size_t)(b * HH + h);
                    if (s == 0)      qb [(bh * TT + t) * DH + d] = (bf16)(v * QSCALE);
                    else if (s == 1) kb [(bh * TT + t) * DH + d] = (bf16)v;
                    else             vtb[(bh * DH + d) * TT + t] = (bf16)v;   // V^T scatter
                }
            }
        }
    }
}

// ---------------- flash attention v6: block-shared LDS, all-reg staging ----------------
// 512 blocks x 256 thr (4 waves). Block owns q-block pair {i, 7-i} (128 rows each)
// of one bh -> uniform 36 KV-tiles. Per tile: K (4KB) + V^T (4KB) reg-staged into
// padded LDS, shared by 4 waves.
__global__ __launch_bounds__(256)
void k_attn(const bf16* __restrict__ qg, const bf16* __restrict__ kg,
            const bf16* __restrict__ vtg, bf16* __restrict__ yb)
{
    __shared__ __align__(16) bf16 sK[2][32 * 72];   // [k-row][dh], row stride 72
    __shared__ __align__(16) bf16 sV[2][64 * 40];   // [d][k],     row stride 40
    __shared__ __align__(16) bf16 sP[4][32 * 40];   // per-wave P tile
    const int tid = threadIdx.x, w = tid >> 6, lane = tid & 63;
    const int l15 = lane & 15, l4 = lane >> 4;

    const int bid = blockIdx.x;          // 0..511
    const int xcd = bid & 7;
    const int j   = bid >> 3;            // 0..63
    const int bh  = xcd * 16 + (j >> 2); // 0..127
    const int qp  = j & 3;               // pair id 0..3

    const bf16* Q  = qg  + (size_t)bh * TT * DH;
    const bf16* Kp = kg  + (size_t)bh * TT * DH;
    const bf16* Vt = vtg + (size_t)bh * DH * TT;
    const int b = bh >> 3, h = bh & 7;

    const int ks_row = tid >> 3;                  // 0..31
    const int ks_col = (tid & 7) * 8;             // 0..56
    const int vs_row = tid >> 2;                  // 0..63 (d)
    const int vs_col = (tid & 3) * 8;             // 0..24

    bf16* myP = &sP[w][0];
    const f32x4 zero = {0.f, 0.f, 0.f, 0.f};

    for (int up = 0; up < 2; ++up) {
        const int qblk = up ? (7 - qp) : qp;   // q-block 0..7 (128 rows)
        const int qbw  = qblk * 128 + w * 32;  // this wave's 32 q-rows
        const int nt   = (qblk + 1) * 4;       // causal KV tiles of 32

        bf16x8 qf[2][2];
#pragma unroll
        for (int mi = 0; mi < 2; ++mi)
#pragma unroll
            for (int kk = 0; kk < 2; ++kk)
                qf[mi][kk] = *(const bf16x8*)(Q + (size_t)(qbw + mi * 16 + l15) * DH + kk * 32 + l4 * 8);

        f32x4 y[2][4];
        float m_[2], lp_[2];
#pragma unroll
        for (int mi = 0; mi < 2; ++mi) {
            m_[mi] = -1e30f; lp_[mi] = 0.f;
#pragma unroll
            for (int dj = 0; dj < 4; ++dj) y[mi][dj] = zero;
        }

        {
            uint4 k0 = *(const uint4*)(Kp + (size_t)ks_row * DH + ks_col);
            uint4 v0 = *(const uint4*)(Vt + (size_t)vs_row * TT + vs_col);
            *(uint4*)(&sK[0][ks_row * 72 + ks_col]) = k0;
            *(uint4*)(&sV[0][vs_row * 40 + vs_col]) = v0;
        }
        __syncthreads();

        for (int t = 0; t < nt; ++t) {
            const int t0 = t * 32;
            const int cur = t & 1, nxt = cur ^ 1;
            const bool more = (t + 1 < nt);
            uint4 kreg, vreg;
            if (more) {   // T14: issue next tile's global loads early
                kreg = *(const uint4*)(Kp + (size_t)(t0 + 32 + ks_row) * DH + ks_col);
                vreg = *(const uint4*)(Vt + (size_t)vs_row * TT + t0 + 32 + vs_col);
            }

            if (t0 <= qbw) {   // wave-uniform causal skip
                bf16x8 kf[2][2];
#pragma unroll
                for (int nj = 0; nj < 2; ++nj) {
                    const int row = nj * 16 + l15;
#pragma unroll
                    for (int kk = 0; kk < 2; ++kk)
                        kf[nj][kk] = *(const bf16x8*)(&sK[cur][row * 72 + ((kk << 2) | l4) * 8]);
                }
                f32x4 s[2][2];
#pragma unroll
                for (int mi = 0; mi < 2; ++mi)
#pragma unroll
                    for (int nj = 0; nj < 2; ++nj) {
                        f32x4 a = mfma16(kf[nj][0], qf[mi][0], zero);
                        s[mi][nj] = mfma16(kf[nj][1], qf[mi][1], a);
                    }
                if (t0 == qbw) {   // diagonal tile mask
#pragma unroll
                    for (int mi = 0; mi < 2; ++mi)
#pragma unroll
                        for (int nj = 0; nj < 2; ++nj)
#pragma unroll
                            for (int rg = 0; rg < 4; ++rg)
                                if (nj * 16 + l4 * 4 + rg > mi * 16 + l15)
                                    s[mi][nj][rg] = -1e30f;
                }
#pragma unroll
                for (int mi = 0; mi < 2; ++mi) {
                    float mx = fmaxf(fmaxf(fmaxf(s[mi][0][0], s[mi][0][1]), fmaxf(s[mi][0][2], s[mi][0][3])),
                                     fmaxf(fmaxf(s[mi][1][0], s[mi][1][1]), fmaxf(s[mi][1][2], s[mi][1][3])));
                    mx = fmaxf(mx, __shfl_xor(mx, 16));
                    mx = fmaxf(mx, __shfl_xor(mx, 32));
                    if (__any(mx > m_[mi] + RESCALE_THR)) {   // T13 defer-rescale
                        float mnew = fmaxf(m_[mi], mx);
                        float corr = exp2f(m_[mi] - mnew);
                        lp_[mi] *= corr;
                        float cr[4];
#pragma unroll
                        for (int rg = 0; rg < 4; ++rg)
                            cr[rg] = __shfl(corr, ((lane >> 4) << 2) | rg);
#pragma unroll
                        for (int dj = 0; dj < 4; ++dj)
#pragma unroll
                            for (int rg = 0; rg < 4; ++rg) y[mi][dj][rg] *= cr[rg];
                        m_[mi] = mnew;
                    }
                    bf16x4 pk0, pk1;
#pragma unroll
                    for (int rg = 0; rg < 4; ++rg) {
                        float p0 = exp2f(s[mi][0][rg] - m_[mi]);
                        float p1 = exp2f(s[mi][1][rg] - m_[mi]);
                        lp_[mi] += p0 + p1;
                        pk0[rg] = (bf16)p0;
                        pk1[rg] = (bf16)p1;
                    }
                    *(bf16x4*)(myP + (mi * 16 + l15) * 40 + l4 * 4)      = pk0;
                    *(bf16x4*)(myP + (mi * 16 + l15) * 40 + 16 + l4 * 4) = pk1;
                }
                bf16x8 pa[2], vf[4];
#pragma unroll
                for (int mi = 0; mi < 2; ++mi)
                    pa[mi] = *(const bf16x8*)(myP + (mi * 16 + l15) * 40 + l4 * 8);
#pragma unroll
                for (int dj = 0; dj < 4; ++dj)
                    vf[dj] = *(const bf16x8*)(&sV[cur][(dj * 16 + l15) * 40 + l4 * 8]);
#pragma unroll
                for (int mi = 0; mi < 2; ++mi)
#pragma unroll
                    for (int dj = 0; dj < 4; ++dj)
                        y[mi][dj] = mfma16(pa[mi], vf[dj], y[mi][dj]);
            }

            if (more) {   // T14: write-late into the other buffer
                *(uint4*)(&sK[nxt][ks_row * 72 + ks_col]) = kreg;
                *(uint4*)(&sV[nxt][vs_row * 40 + vs_col]) = vreg;
            }
            __syncthreads();
        }

        // epilogue: row denominators, normalize, store
#pragma unroll
        for (int mi = 0; mi < 2; ++mi) {
            float lp = lp_[mi];
            lp += __shfl_xor(lp, 16);
            lp += __shfl_xor(lp, 32);
#pragma unroll
            for (int rg = 0; rg < 4; ++rg) {
                float inv = 1.0f / __shfl(lp, ((lane >> 4) << 2) | rg);
                int rr = qbw + mi * 16 + l4 * 4 + rg;
#pragma unroll
                for (int dj = 0; dj < 4; ++dj) {
                    int cc = h * DH + dj * 16 + l15;
                    yb[((size_t)b * TT + rr) * CC + cc] = (bf16)(y[mi][dj][rg] * inv);
                }
            }
        }
        __syncthreads();   // protect sK/sV reuse across up iterations
    }
}

// ---------------- launch ----------------
extern "C" void kernel_launch(void* const* d_in, const int* in_sizes, int n_in,
                              void* d_out, int out_size, void* d_ws, size_t ws_size,
                              hipStream_t stream)
{
    const float* x    = (const float*)d_in[0];   // [16,1024,512]
    const float* wqkv = (const float*)d_in[1];   // [512,1536]
    const float* wout = (const float*)d_in[2];   // [512,512]
    float* out = (float*)d_out;                  // [16,1024,512] fp32

    const size_t NX = (size_t)BB * TT * CC;
    bf16* p   = (bf16*)d_ws;
    bf16* Xb  = p;  p += NX;
    bf16* Wqt = p;  p += (size_t)(3 * CC) * CC;
    bf16* Wot = p;  p += (size_t)CC * CC;
    bf16* Qb  = p;  p += NX;
    bf16* Kb  = p;  p += NX;
    bf16* Vtb = p;  p += NX;
    bf16* Yb  = Xb;                              // alias: Xb dead after GEMM1

    k_cvt  <<<(int)(NX / 4 / 256), 256, 0, stream>>>(x, Xb, (int)NX);
    k_cvt_t<<<(3 * CC * CC + 255) / 256, 256, 0, stream>>>(wqkv, Wqt, CC, 3 * CC);
    k_cvt_t<<<(CC * CC + 255) / 256, 256, 0, stream>>>(wout, Wot, CC, CC);

    // QKV projection with V^T scatter
    k_gemm_bt<1><<<(BB * TT / 128) * (3 * CC / 128), 256, 0, stream>>>(
        Xb, Wqt, BB * TT, 3 * CC, CC, nullptr, Qb, Kb, Vtb);

    // causal flash attention -> Yb
    k_attn<<<512, 256, 0, stream>>>(Qb, Kb, Vtb, Yb);

    // output projection -> fp32 out
    k_gemm_bt<0><<<(BB * TT / 128) * (CC / 128), 256, 0, stream>>>(
        Yb, Wot, BB * TT, CC, CC, out, nullptr, nullptr, nullptr);
}

// Round 15
// 147.162 us; speedup vs baseline: 1.2034x; 1.0624x over previous
//
#include <hip/hip_runtime.h>
#include <hip/hip_bf16.h>

typedef __bf16 bf16;
typedef __bf16 bf16x4 __attribute__((ext_vector_type(4)));
typedef __bf16 bf16x8 __attribute__((ext_vector_type(8)));
typedef float  f32x4  __attribute__((ext_vector_type(4)));

// Problem constants: B=16, T=1024, C=512, H=8, Dh=64
#define BB 16
#define TT 1024
#define CC 512
#define HH 8
#define DH 64

// 0.125 (1/sqrt(Dh)) * log2(e): folded into Q so softmax uses exp2 directly.
#define QSCALE 0.18033688011112042f
#define RESCALE_THR 10.0f

__device__ __forceinline__ void gload16(const void* gsrc, void* ldst) {
    __builtin_amdgcn_global_load_lds(
        (const __attribute__((address_space(1))) void*)gsrc,
        (__attribute__((address_space(3))) void*)ldst, 16, 0, 0);
}

__device__ __forceinline__ f32x4 mfma16(bf16x8 a, bf16x8 b, f32x4 c) {
    return __builtin_amdgcn_mfma_f32_16x16x32_bf16(a, b, c, 0, 0, 0);
}

// ---------------- conversion kernels ----------------
__global__ void k_cvt(const float* __restrict__ src, bf16* __restrict__ dst, int n) {
    int i = (blockIdx.x * blockDim.x + threadIdx.x) * 4;
    if (i < n) {
        float4 v = *(const float4*)(src + i);
        bf16x4 o = { (bf16)v.x, (bf16)v.y, (bf16)v.z, (bf16)v.w };
        *(bf16x4*)(dst + i) = o;
    }
}

__global__ void k_cvt_t(const float* __restrict__ src, bf16* __restrict__ dst, int K, int N) {
    int idx = blockIdx.x * blockDim.x + threadIdx.x;
    if (idx < K * N) {
        int k = idx / N, n = idx - k * N;
        dst[(size_t)n * K + k] = (bf16)src[idx];
    }
}

// ---------------- GEMM: C[M,N] = A[M,K] * Bt[N,K]^T ----------------
// (byte-identical to R14) BK=64, LDS tile [kk][128][32], 16 x 1KB linear
// global_load_lds chunks, XCD-aware swizzle.
template<int MODE>
__global__ __launch_bounds__(256)
void k_gemm_bt(const bf16* __restrict__ A, const bf16* __restrict__ Bt,
               int M, int N, int K,
               float* __restrict__ outF,
               bf16* __restrict__ qb, bf16* __restrict__ kb, bf16* __restrict__ vtb)
{
    __shared__ bf16 sA[2 * 128 * 32];   // [kk][row][32]
    __shared__ bf16 sB[2 * 128 * 32];
    const int tid  = threadIdx.x;
    const int wid  = tid >> 6;
    const int lane = tid & 63;
    const int l15  = lane & 15, l4 = lane >> 4;

    const int cpx = gridDim.x >> 3;
    const int bid = (blockIdx.x & 7) * cpx + (blockIdx.x >> 3);

    const int nNt = N >> 7;
    const int mt  = bid / nNt;
    const int nt  = bid - mt * nNt;
    const int m0  = mt << 7, n0 = nt << 7;
    const int wr  = (wid >> 1) * 64, wc = (wid & 1) * 64;

    f32x4 zero = {0.f, 0.f, 0.f, 0.f};
    f32x4 acc[4][4];
#pragma unroll
    for (int i = 0; i < 4; ++i)
#pragma unroll
        for (int j = 0; j < 4; ++j) acc[i][j] = zero;

    int srow[4], scol[4], soff[4];
#pragma unroll
    for (int c = 0; c < 4; ++c) {
        const int cc = wid * 4 + c;                  // 0..15
        srow[c] = (cc & 7) * 16 + (lane >> 2);       // tile row 0..127
        scol[c] = (cc >> 3) * 32 + (lane & 3) * 8;   // k offset within 64
        soff[c] = cc * 512;                          // LDS elem base (wave-uniform)
    }

    for (int k0 = 0; k0 < K; k0 += 64) {
#pragma unroll
        for (int c = 0; c < 4; ++c)
            gload16(A  + (size_t)(m0 + srow[c]) * K + k0 + scol[c], sA + soff[c]);
#pragma unroll
        for (int c = 0; c < 4; ++c)
            gload16(Bt + (size_t)(n0 + srow[c]) * K + k0 + scol[c], sB + soff[c]);
        __syncthreads();
        bf16x8 af[4][2], bfr[4][2];
#pragma unroll
        for (int kk = 0; kk < 2; ++kk) {
#pragma unroll
            for (int i = 0; i < 4; ++i)
                af[i][kk] = *(const bf16x8*)(sA + kk * 4096 + (wr + i * 16 + l15) * 32 + l4 * 8);
#pragma unroll
            for (int j = 0; j < 4; ++j)
                bfr[j][kk] = *(const bf16x8*)(sB + kk * 4096 + (wc + j * 16 + l15) * 32 + l4 * 8);
        }
#pragma unroll
        for (int kk = 0; kk < 2; ++kk)
#pragma unroll
            for (int i = 0; i < 4; ++i)
#pragma unroll
                for (int j = 0; j < 4; ++j)
                    acc[i][j] = mfma16(af[i][kk], bfr[j][kk], acc[i][j]);
        __syncthreads();
    }

#pragma unroll
    for (int i = 0; i < 4; ++i) {
#pragma unroll
        for (int j = 0; j < 4; ++j) {
#pragma unroll
            for (int rg = 0; rg < 4; ++rg) {
                int rm = m0 + wr + i * 16 + l4 * 4 + rg;
                int cn = n0 + wc + j * 16 + l15;
                float v = acc[i][j][rg];
                if (MODE == 0) {
                    outF[(size_t)rm * N + cn] = v;
                } else {
                    int b = rm >> 10, t = rm & 1023;
                    int s = cn >> 9, h = (cn >> 6) & 7, d = cn & 63;
                    size_t bh = (size_t)(b * HH + h);
                    if (s == 0)      qb [(bh * TT + t) * DH + d] = (bf16)(v * QSCALE);
                    else if (s == 1) kb [(bh * TT + t) * DH + d] = (bf16)v;
                    else             vtb[(bh * DH + d) * TT + t] = (bf16)v;   // V^T scatter
                }
            }
        }
    }
}

// ---------------- flash attention v9: 8 waves x 16 rows, same sync pattern ----------------
// 512 blocks x 512 thr (8 waves). Block owns q-block pair {qp, 7-qp} (128 rows
// each) -> uniform 36 KV-tiles, SAME K/V traffic as v6. Wave w owns 16 q-rows.
// Staging split: threads<256 stage K, >=256 stage V (identical addresses to v6).
// Per-row arithmetic bit-identical to v6; mask in absolute coords (odd waves'
// 16-row slices straddle 32-col tiles).
__global__ __launch_bounds__(512)
void k_attn(const bf16* __restrict__ qg, const bf16* __restrict__ kg,
            const bf16* __restrict__ vtg, bf16* __restrict__ yb)
{
    __shared__ __align__(16) bf16 sK[2][32 * 72];   // [k-row][dh], row stride 72
    __shared__ __align__(16) bf16 sV[2][64 * 40];   // [d][k],     row stride 40
    __shared__ __align__(16) bf16 sP[8][16 * 40];   // per-wave P tile (16 rows)
    const int tid = threadIdx.x, w = tid >> 6, lane = tid & 63;
    const int l15 = lane & 15, l4 = lane >> 4;

    const int bid = blockIdx.x;          // 0..511
    const int xcd = bid & 7;
    const int j   = bid >> 3;            // 0..63
    const int bh  = xcd * 16 + (j >> 2); // 0..127
    const int qp  = j & 3;               // pair id 0..3

    const bf16* Q  = qg  + (size_t)bh * TT * DH;
    const bf16* Kp = kg  + (size_t)bh * TT * DH;
    const bf16* Vt = vtg + (size_t)bh * DH * TT;
    const int b = bh >> 3, h = bh & 7;

    // staging split (wave-uniform branch): waves 0-3 stage K, waves 4-7 stage V
    const bool kstage = (tid < 256);
    const int ks_row = tid >> 3;                  // 0..31 (valid when kstage)
    const int ks_col = (tid & 7) * 8;             // 0..56
    const int t2 = tid & 255;
    const int vs_row = t2 >> 2;                   // 0..63 (d)
    const int vs_col = (t2 & 3) * 8;              // 0..24

    bf16* myP = &sP[w][0];
    const f32x4 zero = {0.f, 0.f, 0.f, 0.f};

    for (int up = 0; up < 2; ++up) {
        const int qblk = up ? (7 - qp) : qp;   // q-block 0..7 (128 rows)
        const int qb   = qblk * 128 + w * 16;  // this wave's 16 q-rows [qb, qb+16)
        const int nt   = (qblk + 1) * 4;       // causal KV tiles of 32

        // Q fragments (MFMA B operand): q-row = qb + l15
        bf16x8 qf[2];
#pragma unroll
        for (int kk = 0; kk < 2; ++kk)
            qf[kk] = *(const bf16x8*)(Q + (size_t)(qb + l15) * DH + kk * 32 + l4 * 8);

        f32x4 y[4];
        float m_ = -1e30f, lp_ = 0.f;
#pragma unroll
        for (int dj = 0; dj < 4; ++dj) y[dj] = zero;

        // prologue: stage tile 0 (split)
        if (kstage) {
            uint4 k0 = *(const uint4*)(Kp + (size_t)ks_row * DH + ks_col);
            *(uint4*)(&sK[0][ks_row * 72 + ks_col]) = k0;
        } else {
            uint4 v0 = *(const uint4*)(Vt + (size_t)vs_row * TT + vs_col);
            *(uint4*)(&sV[0][vs_row * 40 + vs_col]) = v0;
        }
        __syncthreads();

        for (int t = 0; t < nt; ++t) {
            const int t0 = t * 32;
            const int cur = t & 1, nxt = cur ^ 1;
            const bool more = (t + 1 < nt);
            uint4 sreg;
            if (more) {   // T14: issue next tile's global load early
                sreg = kstage
                    ? *(const uint4*)(Kp + (size_t)(t0 + 32 + ks_row) * DH + ks_col)
                    : *(const uint4*)(Vt + (size_t)vs_row * TT + t0 + 32 + vs_col);
            }

            if (t0 < qb + 16) {   // wave-uniform causal skip
                bf16x8 kf[2][2];
#pragma unroll
                for (int nj = 0; nj < 2; ++nj) {
                    const int row = nj * 16 + l15;
#pragma unroll
                    for (int kk = 0; kk < 2; ++kk)
                        kf[nj][kk] = *(const bf16x8*)(&sK[cur][row * 72 + ((kk << 2) | l4) * 8]);
                }
                f32x4 s[2];
#pragma unroll
                for (int nj = 0; nj < 2; ++nj) {
                    f32x4 a = mfma16(kf[nj][0], qf[0], zero);
                    s[nj] = mfma16(kf[nj][1], qf[1], a);
                }
                if (t0 + 32 > qb) {   // straddling tile: absolute-coord mask
#pragma unroll
                    for (int nj = 0; nj < 2; ++nj)
#pragma unroll
                        for (int rg = 0; rg < 4; ++rg)
                            if (t0 + nj * 16 + l4 * 4 + rg > qb + l15)
                                s[nj][rg] = -1e30f;
                }
                // softmax for row qb+l15 (8 in-lane values, xor16/32 reduce)
                float mx = fmaxf(fmaxf(fmaxf(s[0][0], s[0][1]), fmaxf(s[0][2], s[0][3])),
                                 fmaxf(fmaxf(s[1][0], s[1][1]), fmaxf(s[1][2], s[1][3])));
                mx = fmaxf(mx, __shfl_xor(mx, 16));
                mx = fmaxf(mx, __shfl_xor(mx, 32));
                if (__any(mx > m_ + RESCALE_THR)) {   // T13 defer-rescale
                    float mnew = fmaxf(m_, mx);
                    float corr = exp2f(m_ - mnew);
                    lp_ *= corr;
                    float cr[4];
#pragma unroll
                    for (int rg = 0; rg < 4; ++rg)
                        cr[rg] = __shfl(corr, ((lane >> 4) << 2) | rg);
#pragma unroll
                    for (int dj = 0; dj < 4; ++dj)
#pragma unroll
                        for (int rg = 0; rg < 4; ++rg) y[dj][rg] *= cr[rg];
                    m_ = mnew;
                }
                bf16x4 pk0, pk1;
#pragma unroll
                for (int rg = 0; rg < 4; ++rg) {
                    float p0 = exp2f(s[0][rg] - m_);
                    float p1 = exp2f(s[1][rg] - m_);
                    lp_ += p0 + p1;
                    pk0[rg] = (bf16)p0;
                    pk1[rg] = (bf16)p1;
                }
                *(bf16x4*)(myP + l15 * 40 + l4 * 4)      = pk0;
                *(bf16x4*)(myP + l15 * 40 + 16 + l4 * 4) = pk1;

                bf16x8 pa = *(const bf16x8*)(myP + l15 * 40 + l4 * 8);
                bf16x8 vf[4];
#pragma unroll
                for (int dj = 0; dj < 4; ++dj)
                    vf[dj] = *(const bf16x8*)(&sV[cur][(dj * 16 + l15) * 40 + l4 * 8]);
#pragma unroll
                for (int dj = 0; dj < 4; ++dj)
                    y[dj] = mfma16(pa, vf[dj], y[dj]);
            }

            if (more) {   // T14: write-late into the other buffer (split)
                if (kstage) *(uint4*)(&sK[nxt][ks_row * 72 + ks_col]) = sreg;
                else        *(uint4*)(&sV[nxt][vs_row * 40 + vs_col]) = sreg;
            }
            __syncthreads();
        }

        // epilogue: row denominator, redistribute to y-row layout, store
        lp_ += __shfl_xor(lp_, 16);
        lp_ += __shfl_xor(lp_, 32);
#pragma unroll
        for (int rg = 0; rg < 4; ++rg) {
            float inv = 1.0f / __shfl(lp_, ((lane >> 4) << 2) | rg);
            int rr = qb + l4 * 4 + rg;
#pragma unroll
            for (int dj = 0; dj < 4; ++dj) {
                int cc = h * DH + dj * 16 + l15;
                yb[((size_t)b * TT + rr) * CC + cc] = (bf16)(y[dj][rg] * inv);
            }
        }
        __syncthreads();   // protect sK/sV reuse across up iterations
    }
}

// ---------------- launch ----------------
extern "C" void kernel_launch(void* const* d_in, const int* in_sizes, int n_in,
                              void* d_out, int out_size, void* d_ws, size_t ws_size,
                              hipStream_t stream)
{
    const float* x    = (const float*)d_in[0];   // [16,1024,512]
    const float* wqkv = (const float*)d_in[1];   // [512,1536]
    const float* wout = (const float*)d_in[2];   // [512,512]
    float* out = (float*)d_out;                  // [16,1024,512] fp32

    const size_t NX = (size_t)BB * TT * CC;
    bf16* p   = (bf16*)d_ws;
    bf16* Xb  = p;  p += NX;
    bf16* Wqt = p;  p += (size_t)(3 * CC) * CC;
    bf16* Wot = p;  p += (size_t)CC * CC;
    bf16* Qb  = p;  p += NX;
    bf16* Kb  = p;  p += NX;
    bf16* Vtb = p;  p += NX;
    bf16* Yb  = Xb;                              // alias: Xb dead after GEMM1

    k_cvt  <<<(int)(NX / 4 / 256), 256, 0, stream>>>(x, Xb, (int)NX);
    k_cvt_t<<<(3 * CC * CC + 255) / 256, 256, 0, stream>>>(wqkv, Wqt, CC, 3 * CC);
    k_cvt_t<<<(CC * CC + 255) / 256, 256, 0, stream>>>(wout, Wot, CC, CC);

    // QKV projection with V^T scatter
    k_gemm_bt<1><<<(BB * TT / 128) * (3 * CC / 128), 256, 0, stream>>>(
        Xb, Wqt, BB * TT, 3 * CC, CC, nullptr, Qb, Kb, Vtb);

    // causal flash attention -> Yb (512 blocks x 8 waves)
    k_attn<<<512, 512, 0, stream>>>(Qb, Kb, Vtb, Yb);

    // output projection -> fp32 out
    k_gemm_bt<0><<<(BB * TT / 128) * (CC / 128), 256, 0, stream>>>(
        Yb, Wot, BB * TT, CC, CC, out, nullptr, nullptr, nullptr);
}

// Round 16
// 143.424 us; speedup vs baseline: 1.2348x; 1.0261x over previous
//
#include <hip/hip_runtime.h>
#include <hip/hip_bf16.h>

typedef __bf16 bf16;
typedef __bf16 bf16x4 __attribute__((ext_vector_type(4)));
typedef __bf16 bf16x8 __attribute__((ext_vector_type(8)));
typedef float  f32x4  __attribute__((ext_vector_type(4)));

// Problem constants: B=16, T=1024, C=512, H=8, Dh=64
#define BB 16
#define TT 1024
#define CC 512
#define HH 8
#define DH 64

// 0.125 (1/sqrt(Dh)) * log2(e): folded into Q so softmax uses exp2 directly.
#define QSCALE 0.18033688011112042f
#define RESCALE_THR 10.0f

__device__ __forceinline__ void gload16(const void* gsrc, void* ldst) {
    __builtin_amdgcn_global_load_lds(
        (const __attribute__((address_space(1))) void*)gsrc,
        (__attribute__((address_space(3))) void*)ldst, 16, 0, 0);
}

__device__ __forceinline__ f32x4 mfma16(bf16x8 a, bf16x8 b, f32x4 c) {
    return __builtin_amdgcn_mfma_f32_16x16x32_bf16(a, b, c, 0, 0, 0);
}

// ---------------- fused prep: x->bf16, Wqkv^T, Wout^T in one launch ----------------
// Disjoint writes; reads only d_in. Replaces 3 launches (R13 bisect: no setprio).
__global__ __launch_bounds__(256)
void k_prep(const float* __restrict__ x, const float* __restrict__ wqkv,
            const float* __restrict__ wout,
            bf16* __restrict__ xb, bf16* __restrict__ wqt, bf16* __restrict__ wot)
{
    const int stride = gridDim.x * blockDim.x;
    const int i0 = blockIdx.x * blockDim.x + threadIdx.x;
    const int NX4 = BB * TT * CC / 4;
    for (int i = i0; i < NX4; i += stride) {
        float4 v = *(const float4*)(x + (size_t)i * 4);
        bf16x4 o = { (bf16)v.x, (bf16)v.y, (bf16)v.z, (bf16)v.w };
        *(bf16x4*)(xb + (size_t)i * 4) = o;
    }
    const int NQ = CC * 3 * CC;
    for (int i = i0; i < NQ; i += stride) {
        int k = i / (3 * CC), n = i - k * (3 * CC);
        wqt[(size_t)n * CC + k] = (bf16)wqkv[i];
    }
    const int NO = CC * CC;
    for (int i = i0; i < NO; i += stride) {
        int k = i / CC, n = i - k * CC;
        wot[(size_t)n * CC + k] = (bf16)wout[i];
    }
}

// ---------------- GEMM: C[M,N] = A[M,K] * Bt[N,K]^T ----------------
// (byte-identical to R14/R15) BK=64, LDS tile [kk][128][32], 16 x 1KB linear
// global_load_lds chunks, XCD-aware swizzle.
template<int MODE>
__global__ __launch_bounds__(256)
void k_gemm_bt(const bf16* __restrict__ A, const bf16* __restrict__ Bt,
               int M, int N, int K,
               float* __restrict__ outF,
               bf16* __restrict__ qb, bf16* __restrict__ kb, bf16* __restrict__ vtb)
{
    __shared__ bf16 sA[2 * 128 * 32];   // [kk][row][32]
    __shared__ bf16 sB[2 * 128 * 32];
    const int tid  = threadIdx.x;
    const int wid  = tid >> 6;
    const int lane = tid & 63;
    const int l15  = lane & 15, l4 = lane >> 4;

    const int cpx = gridDim.x >> 3;
    const int bid = (blockIdx.x & 7) * cpx + (blockIdx.x >> 3);

    const int nNt = N >> 7;
    const int mt  = bid / nNt;
    const int nt  = bid - mt * nNt;
    const int m0  = mt << 7, n0 = nt << 7;
    const int wr  = (wid >> 1) * 64, wc = (wid & 1) * 64;

    f32x4 zero = {0.f, 0.f, 0.f, 0.f};
    f32x4 acc[4][4];
#pragma unroll
    for (int i = 0; i < 4; ++i)
#pragma unroll
        for (int j = 0; j < 4; ++j) acc[i][j] = zero;

    int srow[4], scol[4], soff[4];
#pragma unroll
    for (int c = 0; c < 4; ++c) {
        const int cc = wid * 4 + c;                  // 0..15
        srow[c] = (cc & 7) * 16 + (lane >> 2);       // tile row 0..127
        scol[c] = (cc >> 3) * 32 + (lane & 3) * 8;   // k offset within 64
        soff[c] = cc * 512;                          // LDS elem base (wave-uniform)
    }

    for (int k0 = 0; k0 < K; k0 += 64) {
#pragma unroll
        for (int c = 0; c < 4; ++c)
            gload16(A  + (size_t)(m0 + srow[c]) * K + k0 + scol[c], sA + soff[c]);
#pragma unroll
        for (int c = 0; c < 4; ++c)
            gload16(Bt + (size_t)(n0 + srow[c]) * K + k0 + scol[c], sB + soff[c]);
        __syncthreads();
        bf16x8 af[4][2], bfr[4][2];
#pragma unroll
        for (int kk = 0; kk < 2; ++kk) {
#pragma unroll
            for (int i = 0; i < 4; ++i)
                af[i][kk] = *(const bf16x8*)(sA + kk * 4096 + (wr + i * 16 + l15) * 32 + l4 * 8);
#pragma unroll
            for (int j = 0; j < 4; ++j)
                bfr[j][kk] = *(const bf16x8*)(sB + kk * 4096 + (wc + j * 16 + l15) * 32 + l4 * 8);
        }
#pragma unroll
        for (int kk = 0; kk < 2; ++kk)
#pragma unroll
            for (int i = 0; i < 4; ++i)
#pragma unroll
                for (int j = 0; j < 4; ++j)
                    acc[i][j] = mfma16(af[i][kk], bfr[j][kk], acc[i][j]);
        __syncthreads();
    }

#pragma unroll
    for (int i = 0; i < 4; ++i) {
#pragma unroll
        for (int j = 0; j < 4; ++j) {
#pragma unroll
            for (int rg = 0; rg < 4; ++rg) {
                int rm = m0 + wr + i * 16 + l4 * 4 + rg;
                int cn = n0 + wc + j * 16 + l15;
                float v = acc[i][j][rg];
                if (MODE == 0) {
                    outF[(size_t)rm * N + cn] = v;
                } else {
                    int b = rm >> 10, t = rm & 1023;
                    int s = cn >> 9, h = (cn >> 6) & 7, d = cn & 63;
                    size_t bh = (size_t)(b * HH + h);
                    if (s == 0)      qb [(bh * TT + t) * DH + d] = (bf16)(v * QSCALE);
                    else if (s == 1) kb [(bh * TT + t) * DH + d] = (bf16)v;
                    else             vtb[(bh * DH + d) * TT + t] = (bf16)v;   // V^T scatter
                }
            }
        }
    }
}

// ---------------- flash attention v9: 8 waves x 16 rows (byte-identical to R15) ----------------
__global__ __launch_bounds__(512)
void k_attn(const bf16* __restrict__ qg, const bf16* __restrict__ kg,
            const bf16* __restrict__ vtg, bf16* __restrict__ yb)
{
    __shared__ __align__(16) bf16 sK[2][32 * 72];   // [k-row][dh], row stride 72
    __shared__ __align__(16) bf16 sV[2][64 * 40];   // [d][k],     row stride 40
    __shared__ __align__(16) bf16 sP[8][16 * 40];   // per-wave P tile (16 rows)
    const int tid = threadIdx.x, w = tid >> 6, lane = tid & 63;
    const int l15 = lane & 15, l4 = lane >> 4;

    const int bid = blockIdx.x;          // 0..511
    const int xcd = bid & 7;
    const int j   = bid >> 3;            // 0..63
    const int bh  = xcd * 16 + (j >> 2); // 0..127
    const int qp  = j & 3;               // pair id 0..3

    const bf16* Q  = qg  + (size_t)bh * TT * DH;
    const bf16* Kp = kg  + (size_t)bh * TT * DH;
    const bf16* Vt = vtg + (size_t)bh * DH * TT;
    const int b = bh >> 3, h = bh & 7;

    const bool kstage = (tid < 256);
    const int ks_row = tid >> 3;                  // 0..31 (valid when kstage)
    const int ks_col = (tid & 7) * 8;             // 0..56
    const int t2 = tid & 255;
    const int vs_row = t2 >> 2;                   // 0..63 (d)
    const int vs_col = (t2 & 3) * 8;              // 0..24

    bf16* myP = &sP[w][0];
    const f32x4 zero = {0.f, 0.f, 0.f, 0.f};

    for (int up = 0; up < 2; ++up) {
        const int qblk = up ? (7 - qp) : qp;   // q-block 0..7 (128 rows)
        const int qb   = qblk * 128 + w * 16;  // this wave's 16 q-rows [qb, qb+16)
        const int nt   = (qblk + 1) * 4;       // causal KV tiles of 32

        bf16x8 qf[2];
#pragma unroll
        for (int kk = 0; kk < 2; ++kk)
            qf[kk] = *(const bf16x8*)(Q + (size_t)(qb + l15) * DH + kk * 32 + l4 * 8);

        f32x4 y[4];
        float m_ = -1e30f, lp_ = 0.f;
#pragma unroll
        for (int dj = 0; dj < 4; ++dj) y[dj] = zero;

        if (kstage) {
            uint4 k0 = *(const uint4*)(Kp + (size_t)ks_row * DH + ks_col);
            *(uint4*)(&sK[0][ks_row * 72 + ks_col]) = k0;
        } else {
            uint4 v0 = *(const uint4*)(Vt + (size_t)vs_row * TT + vs_col);
            *(uint4*)(&sV[0][vs_row * 40 + vs_col]) = v0;
        }
        __syncthreads();

        for (int t = 0; t < nt; ++t) {
            const int t0 = t * 32;
            const int cur = t & 1, nxt = cur ^ 1;
            const bool more = (t + 1 < nt);
            uint4 sreg;
            if (more) {   // T14: issue next tile's global load early
                sreg = kstage
                    ? *(const uint4*)(Kp + (size_t)(t0 + 32 + ks_row) * DH + ks_col)
                    : *(const uint4*)(Vt + (size_t)vs_row * TT + t0 + 32 + vs_col);
            }

            if (t0 < qb + 16) {   // wave-uniform causal skip
                bf16x8 kf[2][2];
#pragma unroll
                for (int nj = 0; nj < 2; ++nj) {
                    const int row = nj * 16 + l15;
#pragma unroll
                    for (int kk = 0; kk < 2; ++kk)
                        kf[nj][kk] = *(const bf16x8*)(&sK[cur][row * 72 + ((kk << 2) | l4) * 8]);
                }
                f32x4 s[2];
#pragma unroll
                for (int nj = 0; nj < 2; ++nj) {
                    f32x4 a = mfma16(kf[nj][0], qf[0], zero);
                    s[nj] = mfma16(kf[nj][1], qf[1], a);
                }
                if (t0 + 32 > qb) {   // straddling tile: absolute-coord mask
#pragma unroll
                    for (int nj = 0; nj < 2; ++nj)
#pragma unroll
                        for (int rg = 0; rg < 4; ++rg)
                            if (t0 + nj * 16 + l4 * 4 + rg > qb + l15)
                                s[nj][rg] = -1e30f;
                }
                float mx = fmaxf(fmaxf(fmaxf(s[0][0], s[0][1]), fmaxf(s[0][2], s[0][3])),
                                 fmaxf(fmaxf(s[1][0], s[1][1]), fmaxf(s[1][2], s[1][3])));
                mx = fmaxf(mx, __shfl_xor(mx, 16));
                mx = fmaxf(mx, __shfl_xor(mx, 32));
                if (__any(mx > m_ + RESCALE_THR)) {   // T13 defer-rescale
                    float mnew = fmaxf(m_, mx);
                    float corr = exp2f(m_ - mnew);
                    lp_ *= corr;
                    float cr[4];
#pragma unroll
                    for (int rg = 0; rg < 4; ++rg)
                        cr[rg] = __shfl(corr, ((lane >> 4) << 2) | rg);
#pragma unroll
                    for (int dj = 0; dj < 4; ++dj)
#pragma unroll
                        for (int rg = 0; rg < 4; ++rg) y[dj][rg] *= cr[rg];
                    m_ = mnew;
                }
                bf16x4 pk0, pk1;
#pragma unroll
                for (int rg = 0; rg < 4; ++rg) {
                    float p0 = exp2f(s[0][rg] - m_);
                    float p1 = exp2f(s[1][rg] - m_);
                    lp_ += p0 + p1;
                    pk0[rg] = (bf16)p0;
                    pk1[rg] = (bf16)p1;
                }
                *(bf16x4*)(myP + l15 * 40 + l4 * 4)      = pk0;
                *(bf16x4*)(myP + l15 * 40 + 16 + l4 * 4) = pk1;

                bf16x8 pa = *(const bf16x8*)(myP + l15 * 40 + l4 * 8);
                bf16x8 vf[4];
#pragma unroll
                for (int dj = 0; dj < 4; ++dj)
                    vf[dj] = *(const bf16x8*)(&sV[cur][(dj * 16 + l15) * 40 + l4 * 8]);
#pragma unroll
                for (int dj = 0; dj < 4; ++dj)
                    y[dj] = mfma16(pa, vf[dj], y[dj]);
            }

            if (more) {   // T14: write-late into the other buffer (split)
                if (kstage) *(uint4*)(&sK[nxt][ks_row * 72 + ks_col]) = sreg;
                else        *(uint4*)(&sV[nxt][vs_row * 40 + vs_col]) = sreg;
            }
            __syncthreads();
        }

        // epilogue: row denominator, redistribute to y-row layout, store
        lp_ += __shfl_xor(lp_, 16);
        lp_ += __shfl_xor(lp_, 32);
#pragma unroll
        for (int rg = 0; rg < 4; ++rg) {
            float inv = 1.0f / __shfl(lp_, ((lane >> 4) << 2) | rg);
            int rr = qb + l4 * 4 + rg;
#pragma unroll
            for (int dj = 0; dj < 4; ++dj) {
                int cc = h * DH + dj * 16 + l15;
                yb[((size_t)b * TT + rr) * CC + cc] = (bf16)(y[dj][rg] * inv);
            }
        }
        __syncthreads();   // protect sK/sV reuse across up iterations
    }
}

// ---------------- launch ----------------
extern "C" void kernel_launch(void* const* d_in, const int* in_sizes, int n_in,
                              void* d_out, int out_size, void* d_ws, size_t ws_size,
                              hipStream_t stream)
{
    const float* x    = (const float*)d_in[0];   // [16,1024,512]
    const float* wqkv = (const float*)d_in[1];   // [512,1536]
    const float* wout = (const float*)d_in[2];   // [512,512]
    float* out = (float*)d_out;                  // [16,1024,512] fp32

    const size_t NX = (size_t)BB * TT * CC;
    bf16* p   = (bf16*)d_ws;
    bf16* Xb  = p;  p += NX;
    bf16* Wqt = p;  p += (size_t)(3 * CC) * CC;
    bf16* Wot = p;  p += (size_t)CC * CC;
    bf16* Qb  = p;  p += NX;
    bf16* Kb  = p;  p += NX;
    bf16* Vtb = p;  p += NX;
    bf16* Yb  = Xb;                              // alias: Xb dead after GEMM1

    // fused conversions (one launch)
    k_prep<<<2048, 256, 0, stream>>>(x, wqkv, wout, Xb, Wqt, Wot);

    // QKV projection with V^T scatter
    k_gemm_bt<1><<<(BB * TT / 128) * (3 * CC / 128), 256, 0, stream>>>(
        Xb, Wqt, BB * TT, 3 * CC, CC, nullptr, Qb, Kb, Vtb);

    // causal flash attention -> Yb (512 blocks x 8 waves)
    k_attn<<<512, 512, 0, stream>>>(Qb, Kb, Vtb, Yb);

    // output projection -> fp32 out
    k_gemm_bt<0><<<(BB * TT / 128) * (CC / 128), 256, 0, stream>>>(
        Yb, Wot, BB * TT, CC, CC, out, nullptr, nullptr, nullptr);
}

// Round 17
// 123.063 us; speedup vs baseline: 1.4391x; 1.1655x over previous
//
#include <hip/hip_runtime.h>
#include <hip/hip_bf16.h>

typedef __bf16 bf16;
typedef __bf16 bf16x4 __attribute__((ext_vector_type(4)));
typedef __bf16 bf16x8 __attribute__((ext_vector_type(8)));
typedef float  f32x4  __attribute__((ext_vector_type(4)));

// Problem constants: B=16, T=1024, C=512, H=8, Dh=64
#define BB 16
#define TT 1024
#define CC 512
#define HH 8
#define DH 64

// 0.125 (1/sqrt(Dh)) * log2(e): folded into Q so softmax uses exp2 directly.
#define QSCALE 0.18033688011112042f
#define RESCALE_THR 10.0f

__device__ __forceinline__ void gload16(const void* gsrc, void* ldst) {
    __builtin_amdgcn_global_load_lds(
        (const __attribute__((address_space(1))) void*)gsrc,
        (__attribute__((address_space(3))) void*)ldst, 16, 0, 0);
}

__device__ __forceinline__ f32x4 mfma16(bf16x8 a, bf16x8 b, f32x4 c) {
    return __builtin_amdgcn_mfma_f32_16x16x32_bf16(a, b, c, 0, 0, 0);
}

// ---------------- fused prep: x->bf16, Wqkv^T, Wout^T in one launch ----------------
__global__ __launch_bounds__(256)
void k_prep(const float* __restrict__ x, const float* __restrict__ wqkv,
            const float* __restrict__ wout,
            bf16* __restrict__ xb, bf16* __restrict__ wqt, bf16* __restrict__ wot)
{
    const int stride = gridDim.x * blockDim.x;
    const int i0 = blockIdx.x * blockDim.x + threadIdx.x;
    const int NX4 = BB * TT * CC / 4;
    for (int i = i0; i < NX4; i += stride) {
        float4 v = *(const float4*)(x + (size_t)i * 4);
        bf16x4 o = { (bf16)v.x, (bf16)v.y, (bf16)v.z, (bf16)v.w };
        *(bf16x4*)(xb + (size_t)i * 4) = o;
    }
    const int NQ = CC * 3 * CC;
    for (int i = i0; i < NQ; i += stride) {
        int k = i / (3 * CC), n = i - k * (3 * CC);
        wqt[(size_t)n * CC + k] = (bf16)wqkv[i];
    }
    const int NO = CC * CC;
    for (int i = i0; i < NO; i += stride) {
        int k = i / CC, n = i - k * CC;
        wot[(size_t)n * CC + k] = (bf16)wout[i];
    }
}

// ---------------- GEMM: C[M,N] = A[M,K] * Bt[N,K]^T ----------------
// R17 delta vs R16: MFMA operand order swapped (bfr first) so the accumulator's
// rg index spans 4 CONSECUTIVE COLUMNS: rm = m0+wr+i*16+l15 (per i),
// cn = n0+wc+j*16+l4*4+rg. Same values, transposed register layout ->
// vectorized epilogue: MODE 0 f32x4 stores; MODE 1 Q/K bf16x4 stores.
// K-loop, staging, swizzle byte-identical to R16.
template<int MODE>
__global__ __launch_bounds__(256)
void k_gemm_bt(const bf16* __restrict__ A, const bf16* __restrict__ Bt,
               int M, int N, int K,
               float* __restrict__ outF,
               bf16* __restrict__ qb, bf16* __restrict__ kb, bf16* __restrict__ vtb)
{
    __shared__ bf16 sA[2 * 128 * 32];   // [kk][row][32]
    __shared__ bf16 sB[2 * 128 * 32];
    const int tid  = threadIdx.x;
    const int wid  = tid >> 6;
    const int lane = tid & 63;
    const int l15  = lane & 15, l4 = lane >> 4;

    const int cpx = gridDim.x >> 3;
    const int bid = (blockIdx.x & 7) * cpx + (blockIdx.x >> 3);

    const int nNt = N >> 7;
    const int mt  = bid / nNt;
    const int nt  = bid - mt * nNt;
    const int m0  = mt << 7, n0 = nt << 7;
    const int wr  = (wid >> 1) * 64, wc = (wid & 1) * 64;

    f32x4 zero = {0.f, 0.f, 0.f, 0.f};
    f32x4 acc[4][4];
#pragma unroll
    for (int i = 0; i < 4; ++i)
#pragma unroll
        for (int j = 0; j < 4; ++j) acc[i][j] = zero;

    int srow[4], scol[4], soff[4];
#pragma unroll
    for (int c = 0; c < 4; ++c) {
        const int cc = wid * 4 + c;                  // 0..15
        srow[c] = (cc & 7) * 16 + (lane >> 2);       // tile row 0..127
        scol[c] = (cc >> 3) * 32 + (lane & 3) * 8;   // k offset within 64
        soff[c] = cc * 512;                          // LDS elem base (wave-uniform)
    }

    for (int k0 = 0; k0 < K; k0 += 64) {
#pragma unroll
        for (int c = 0; c < 4; ++c)
            gload16(A  + (size_t)(m0 + srow[c]) * K + k0 + scol[c], sA + soff[c]);
#pragma unroll
        for (int c = 0; c < 4; ++c)
            gload16(Bt + (size_t)(n0 + srow[c]) * K + k0 + scol[c], sB + soff[c]);
        __syncthreads();
        bf16x8 af[4][2], bfr[4][2];
#pragma unroll
        for (int kk = 0; kk < 2; ++kk) {
#pragma unroll
            for (int i = 0; i < 4; ++i)
                af[i][kk] = *(const bf16x8*)(sA + kk * 4096 + (wr + i * 16 + l15) * 32 + l4 * 8);
#pragma unroll
            for (int j = 0; j < 4; ++j)
                bfr[j][kk] = *(const bf16x8*)(sB + kk * 4096 + (wc + j * 16 + l15) * 32 + l4 * 8);
        }
#pragma unroll
        for (int kk = 0; kk < 2; ++kk)
#pragma unroll
            for (int i = 0; i < 4; ++i)
#pragma unroll
                for (int j = 0; j < 4; ++j)
                    acc[i][j] = mfma16(bfr[j][kk], af[i][kk], acc[i][j]);   // swapped
        __syncthreads();
    }

    // vectorized epilogue: rm per (i); cn0..cn0+3 contiguous per (i,j)
#pragma unroll
    for (int i = 0; i < 4; ++i) {
        const int rm = m0 + wr + i * 16 + l15;
#pragma unroll
        for (int j = 0; j < 4; ++j) {
            const int cn0 = n0 + wc + j * 16 + l4 * 4;
            if (MODE == 0) {
                *(f32x4*)(&outF[(size_t)rm * N + cn0]) = acc[i][j];
            } else {
                int b = rm >> 10, t = rm & 1023;
                int s = cn0 >> 9, h = (cn0 >> 6) & 7, d0 = cn0 & 63;
                size_t bh = (size_t)(b * HH + h);
                if (s == 0) {
                    bf16x4 o = { (bf16)(acc[i][j][0] * QSCALE), (bf16)(acc[i][j][1] * QSCALE),
                                 (bf16)(acc[i][j][2] * QSCALE), (bf16)(acc[i][j][3] * QSCALE) };
                    *(bf16x4*)(qb + (bh * TT + t) * DH + d0) = o;
                } else if (s == 1) {
                    bf16x4 o = { (bf16)acc[i][j][0], (bf16)acc[i][j][1],
                                 (bf16)acc[i][j][2], (bf16)acc[i][j][3] };
                    *(bf16x4*)(kb + (bh * TT + t) * DH + d0) = o;
                } else {
#pragma unroll
                    for (int rg = 0; rg < 4; ++rg)
                        vtb[(bh * DH + d0 + rg) * TT + t] = (bf16)acc[i][j][rg];
                }
            }
        }
    }
}

// ---------------- flash attention v9: 8 waves x 16 rows (byte-identical to R15/R16) ----------------
__global__ __launch_bounds__(512)
void k_attn(const bf16* __restrict__ qg, const bf16* __restrict__ kg,
            const bf16* __restrict__ vtg, bf16* __restrict__ yb)
{
    __shared__ __align__(16) bf16 sK[2][32 * 72];   // [k-row][dh], row stride 72
    __shared__ __align__(16) bf16 sV[2][64 * 40];   // [d][k],     row stride 40
    __shared__ __align__(16) bf16 sP[8][16 * 40];   // per-wave P tile (16 rows)
    const int tid = threadIdx.x, w = tid >> 6, lane = tid & 63;
    const int l15 = lane & 15, l4 = lane >> 4;

    const int bid = blockIdx.x;          // 0..511
    const int xcd = bid & 7;
    const int j   = bid >> 3;            // 0..63
    const int bh  = xcd * 16 + (j >> 2); // 0..127
    const int qp  = j & 3;               // pair id 0..3

    const bf16* Q  = qg  + (size_t)bh * TT * DH;
    const bf16* Kp = kg  + (size_t)bh * TT * DH;
    const bf16* Vt = vtg + (size_t)bh * DH * TT;
    const int b = bh >> 3, h = bh & 7;

    const bool kstage = (tid < 256);
    const int ks_row = tid >> 3;                  // 0..31 (valid when kstage)
    const int ks_col = (tid & 7) * 8;             // 0..56
    const int t2 = tid & 255;
    const int vs_row = t2 >> 2;                   // 0..63 (d)
    const int vs_col = (t2 & 3) * 8;              // 0..24

    bf16* myP = &sP[w][0];
    const f32x4 zero = {0.f, 0.f, 0.f, 0.f};

    for (int up = 0; up < 2; ++up) {
        const int qblk = up ? (7 - qp) : qp;   // q-block 0..7 (128 rows)
        const int qb   = qblk * 128 + w * 16;  // this wave's 16 q-rows [qb, qb+16)
        const int nt   = (qblk + 1) * 4;       // causal KV tiles of 32

        bf16x8 qf[2];
#pragma unroll
        for (int kk = 0; kk < 2; ++kk)
            qf[kk] = *(const bf16x8*)(Q + (size_t)(qb + l15) * DH + kk * 32 + l4 * 8);

        f32x4 y[4];
        float m_ = -1e30f, lp_ = 0.f;
#pragma unroll
        for (int dj = 0; dj < 4; ++dj) y[dj] = zero;

        if (kstage) {
            uint4 k0 = *(const uint4*)(Kp + (size_t)ks_row * DH + ks_col);
            *(uint4*)(&sK[0][ks_row * 72 + ks_col]) = k0;
        } else {
            uint4 v0 = *(const uint4*)(Vt + (size_t)vs_row * TT + vs_col);
            *(uint4*)(&sV[0][vs_row * 40 + vs_col]) = v0;
        }
        __syncthreads();

        for (int t = 0; t < nt; ++t) {
            const int t0 = t * 32;
            const int cur = t & 1, nxt = cur ^ 1;
            const bool more = (t + 1 < nt);
            uint4 sreg;
            if (more) {   // T14: issue next tile's global load early
                sreg = kstage
                    ? *(const uint4*)(Kp + (size_t)(t0 + 32 + ks_row) * DH + ks_col)
                    : *(const uint4*)(Vt + (size_t)vs_row * TT + t0 + 32 + vs_col);
            }

            if (t0 < qb + 16) {   // wave-uniform causal skip
                bf16x8 kf[2][2];
#pragma unroll
                for (int nj = 0; nj < 2; ++nj) {
                    const int row = nj * 16 + l15;
#pragma unroll
                    for (int kk = 0; kk < 2; ++kk)
                        kf[nj][kk] = *(const bf16x8*)(&sK[cur][row * 72 + ((kk << 2) | l4) * 8]);
                }
                f32x4 s[2];
#pragma unroll
                for (int nj = 0; nj < 2; ++nj) {
                    f32x4 a = mfma16(kf[nj][0], qf[0], zero);
                    s[nj] = mfma16(kf[nj][1], qf[1], a);
                }
                if (t0 + 32 > qb) {   // straddling tile: absolute-coord mask
#pragma unroll
                    for (int nj = 0; nj < 2; ++nj)
#pragma unroll
                        for (int rg = 0; rg < 4; ++rg)
                            if (t0 + nj * 16 + l4 * 4 + rg > qb + l15)
                                s[nj][rg] = -1e30f;
                }
                float mx = fmaxf(fmaxf(fmaxf(s[0][0], s[0][1]), fmaxf(s[0][2], s[0][3])),
                                 fmaxf(fmaxf(s[1][0], s[1][1]), fmaxf(s[1][2], s[1][3])));
                mx = fmaxf(mx, __shfl_xor(mx, 16));
                mx = fmaxf(mx, __shfl_xor(mx, 32));
                if (__any(mx > m_ + RESCALE_THR)) {   // T13 defer-rescale
                    float mnew = fmaxf(m_, mx);
                    float corr = exp2f(m_ - mnew);
                    lp_ *= corr;
                    float cr[4];
#pragma unroll
                    for (int rg = 0; rg < 4; ++rg)
                        cr[rg] = __shfl(corr, ((lane >> 4) << 2) | rg);
#pragma unroll
                    for (int dj = 0; dj < 4; ++dj)
#pragma unroll
                        for (int rg = 0; rg < 4; ++rg) y[dj][rg] *= cr[rg];
                    m_ = mnew;
                }
                bf16x4 pk0, pk1;
#pragma unroll
                for (int rg = 0; rg < 4; ++rg) {
                    float p0 = exp2f(s[0][rg] - m_);
                    float p1 = exp2f(s[1][rg] - m_);
                    lp_ += p0 + p1;
                    pk0[rg] = (bf16)p0;
                    pk1[rg] = (bf16)p1;
                }
                *(bf16x4*)(myP + l15 * 40 + l4 * 4)      = pk0;
                *(bf16x4*)(myP + l15 * 40 + 16 + l4 * 4) = pk1;

                bf16x8 pa = *(const bf16x8*)(myP + l15 * 40 + l4 * 8);
                bf16x8 vf[4];
#pragma unroll
                for (int dj = 0; dj < 4; ++dj)
                    vf[dj] = *(const bf16x8*)(&sV[cur][(dj * 16 + l15) * 40 + l4 * 8]);
#pragma unroll
                for (int dj = 0; dj < 4; ++dj)
                    y[dj] = mfma16(pa, vf[dj], y[dj]);
            }

            if (more) {   // T14: write-late into the other buffer (split)
                if (kstage) *(uint4*)(&sK[nxt][ks_row * 72 + ks_col]) = sreg;
                else        *(uint4*)(&sV[nxt][vs_row * 40 + vs_col]) = sreg;
            }
            __syncthreads();
        }

        // epilogue: row denominator, redistribute to y-row layout, store
        lp_ += __shfl_xor(lp_, 16);
        lp_ += __shfl_xor(lp_, 32);
#pragma unroll
        for (int rg = 0; rg < 4; ++rg) {
            float inv = 1.0f / __shfl(lp_, ((lane >> 4) << 2) | rg);
            int rr = qb + l4 * 4 + rg;
#pragma unroll
            for (int dj = 0; dj < 4; ++dj) {
                int cc = h * DH + dj * 16 + l15;
                yb[((size_t)b * TT + rr) * CC + cc] = (bf16)(y[dj][rg] * inv);
            }
        }
        __syncthreads();   // protect sK/sV reuse across up iterations
    }
}

// ---------------- launch ----------------
extern "C" void kernel_launch(void* const* d_in, const int* in_sizes, int n_in,
                              void* d_out, int out_size, void* d_ws, size_t ws_size,
                              hipStream_t stream)
{
    const float* x    = (const float*)d_in[0];   // [16,1024,512]
    const float* wqkv = (const float*)d_in[1];   // [512,1536]
    const float* wout = (const float*)d_in[2];   // [512,512]
    float* out = (float*)d_out;                  // [16,1024,512] fp32

    const size_t NX = (size_t)BB * TT * CC;
    bf16* p   = (bf16*)d_ws;
    bf16* Xb  = p;  p += NX;
    bf16* Wqt = p;  p += (size_t)(3 * CC) * CC;
    bf16* Wot = p;  p += (size_t)CC * CC;
    bf16* Qb  = p;  p += NX;
    bf16* Kb  = p;  p += NX;
    bf16* Vtb = p;  p += NX;
    bf16* Yb  = Xb;                              // alias: Xb dead after GEMM1

    // fused conversions (one launch)
    k_prep<<<2048, 256, 0, stream>>>(x, wqkv, wout, Xb, Wqt, Wot);

    // QKV projection with V^T scatter
    k_gemm_bt<1><<<(BB * TT / 128) * (3 * CC / 128), 256, 0, stream>>>(
        Xb, Wqt, BB * TT, 3 * CC, CC, nullptr, Qb, Kb, Vtb);

    // causal flash attention -> Yb (512 blocks x 8 waves)
    k_attn<<<512, 512, 0, stream>>>(Qb, Kb, Vtb, Yb);

    // output projection -> fp32 out
    k_gemm_bt<0><<<(BB * TT / 128) * (CC / 128), 256, 0, stream>>>(
        Yb, Wot, BB * TT, CC, CC, out, nullptr, nullptr, nullptr);
}